// Round 1
// baseline (1142.142 us; speedup 1.0000x reference)
//
#include <hip/hip_runtime.h>
#include <math.h>

// Problem constants (from reference): N=100000 nodes, E=1600000 edges,
// features 128 -> 64 -> 64 -> 1.
#define NN 100000
#define NE 1600000

// ---------------------------------------------------------------------------
// Degree / normalization: dis[i] = rsqrt(deg[i]) where deg counts incoming
// edges (by dst) plus the self-loop. deg >= 1 always, so no zero guard needed.
// ---------------------------------------------------------------------------
__global__ void k_init_deg(float* __restrict__ dis) {
    int i = blockIdx.x * 256 + threadIdx.x;
    if (i < NN) dis[i] = 1.0f;  // self-loop contribution
}

__global__ void k_count_deg(const int* __restrict__ dst, float* __restrict__ dis) {
    int e = blockIdx.x * 256 + threadIdx.x;
    if (e < NE) atomicAdd(&dis[dst[e]], 1.0f);
}

__global__ void k_finalize_dis(float* __restrict__ dis) {
    int i = blockIdx.x * 256 + threadIdx.x;
    if (i < NN) dis[i] = rsqrtf(dis[i]);
}

// ---------------------------------------------------------------------------
// Layer 1 GEMM: ts[row][c] = (sum_k x[row][k] * W1[k][c]) * dis[row]
// Also writes u = ts (the self-loop init of the aggregation buffer).
// Block = 256 threads = 4 rows x 64 cols. W1 (128x64 f32 = 32 KB) in LDS.
// ---------------------------------------------------------------------------
__global__ __launch_bounds__(256) void k_gemm1(
    const float* __restrict__ x, const float* __restrict__ W,
    const float* __restrict__ dis, float* __restrict__ ts, float* __restrict__ u) {
    __shared__ float Ws[128 * 64];
    __shared__ float xs[4 * 128];
    int t = threadIdx.x;
    for (int i = t; i < 128 * 64; i += 256) Ws[i] = W[i];
    int row0 = blockIdx.x * 4;
    for (int i = t; i < 4 * 128; i += 256) {
        xs[i] = x[(row0 + (i >> 7)) * 128 + (i & 127)];
    }
    __syncthreads();
    int lr = t >> 6;        // local row 0..3
    int col = t & 63;
    int row = row0 + lr;
    float acc = 0.0f;
#pragma unroll
    for (int k = 0; k < 128; ++k) acc += xs[lr * 128 + k] * Ws[k * 64 + col];
    float v = acc * dis[row];
    ts[row * 64 + col] = v;
    u[row * 64 + col] = v;
}

// ---------------------------------------------------------------------------
// Layer 2 GEMM: same structure, K=64. Note u may alias h's buffer: each block
// reads its own 4 rows of h into LDS (with a barrier) before writing u for
// those same rows, and no block touches another block's rows.
// ---------------------------------------------------------------------------
__global__ __launch_bounds__(256) void k_gemm2(
    const float* __restrict__ h, const float* __restrict__ W,
    const float* __restrict__ dis, float* __restrict__ ts, float* __restrict__ u) {
    __shared__ float Ws[64 * 64];
    __shared__ float hs[4 * 64];
    int t = threadIdx.x;
    for (int i = t; i < 64 * 64; i += 256) Ws[i] = W[i];
    int row0 = blockIdx.x * 4;
    hs[t] = h[row0 * 64 + t];  // 256 = 4 rows x 64 exactly
    __syncthreads();
    int lr = t >> 6;
    int col = t & 63;
    int row = row0 + lr;
    float acc = 0.0f;
#pragma unroll
    for (int k = 0; k < 64; ++k) acc += hs[lr * 64 + k] * Ws[k * 64 + col];
    float v = acc * dis[row];
    ts[row * 64 + col] = v;
    u[row * 64 + col] = v;
}

// ---------------------------------------------------------------------------
// Edge aggregation (64-wide features): one quarter-wave... actually one
// 64-lane group per edge; lane = feature channel. Gather ts[src] (coalesced
// 256B) and atomicAdd into u[dst].
// ---------------------------------------------------------------------------
__global__ __launch_bounds__(256) void k_edge_agg64(
    const int* __restrict__ src, const int* __restrict__ dst,
    const float* __restrict__ ts, float* __restrict__ u) {
    int e = blockIdx.x * 4 + (threadIdx.x >> 6);
    if (e >= NE) return;
    int lane = threadIdx.x & 63;
    int s = src[e];
    int d = dst[e];
    atomicAdd(&u[d * 64 + lane], ts[s * 64 + lane]);
}

// ---------------------------------------------------------------------------
// Epilogue: h = relu(u * dis[row] + b[col])
// ---------------------------------------------------------------------------
__global__ void k_relu_bias(const float* __restrict__ u, const float* __restrict__ dis,
                            const float* __restrict__ b, float* __restrict__ h) {
    int i = blockIdx.x * 256 + threadIdx.x;  // over N*64
    int row = i >> 6;
    int col = i & 63;
    float v = u[i] * dis[row] + b[col];
    h[i] = v > 0.0f ? v : 0.0f;
}

// ---------------------------------------------------------------------------
// Layer 3: t3[row] = (sum_k h[row][k] * W3[k]) * dis[row]; u3 init = t3.
// ---------------------------------------------------------------------------
__global__ void k_gemm3(const float* __restrict__ h, const float* __restrict__ W3,
                        const float* __restrict__ dis, float* __restrict__ t3,
                        float* __restrict__ u3) {
    __shared__ float Ws[64];
    if (threadIdx.x < 64) Ws[threadIdx.x] = W3[threadIdx.x];
    __syncthreads();
    int row = blockIdx.x * 256 + threadIdx.x;
    if (row >= NN) return;
    const float4* hp = (const float4*)(h + row * 64);
    float acc = 0.0f;
#pragma unroll
    for (int k = 0; k < 16; ++k) {
        float4 hv = hp[k];
        acc += hv.x * Ws[4 * k] + hv.y * Ws[4 * k + 1] + hv.z * Ws[4 * k + 2] + hv.w * Ws[4 * k + 3];
    }
    float v = acc * dis[row];
    t3[row] = v;
    u3[row] = v;
}

__global__ void k_edge_agg1(const int* __restrict__ src, const int* __restrict__ dst,
                            const float* __restrict__ t3, float* __restrict__ u3) {
    int e = blockIdx.x * 256 + threadIdx.x;
    if (e < NE) atomicAdd(&u3[dst[e]], t3[src[e]]);
}

__global__ void k_sigmoid(const float* __restrict__ u3, const float* __restrict__ dis,
                          const float* __restrict__ b3, float* __restrict__ out) {
    int i = blockIdx.x * 256 + threadIdx.x;
    if (i >= NN) return;
    float z = u3[i] * dis[i] + b3[0];
    out[i] = 1.0f / (1.0f + __expf(-z));
}

// ---------------------------------------------------------------------------
extern "C" void kernel_launch(void* const* d_in, const int* in_sizes, int n_in,
                              void* d_out, int out_size, void* d_ws, size_t ws_size,
                              hipStream_t stream) {
    const float* x  = (const float*)d_in[0];   // N x 128
    const float* W1 = (const float*)d_in[1];   // 128 x 64
    const float* b1 = (const float*)d_in[2];   // 64
    const float* W2 = (const float*)d_in[3];   // 64 x 64
    const float* b2 = (const float*)d_in[4];   // 64
    const float* W3 = (const float*)d_in[5];   // 64 x 1
    const float* b3 = (const float*)d_in[6];   // 1
    const int*   ei = (const int*)d_in[7];     // 2 x E (src row then dst row)
    const int* src = ei;
    const int* dst = ei + NE;
    float* out = (float*)d_out;

    // Workspace layout (floats):
    float* A   = (float*)d_ws;            // N*64
    float* B   = A + (size_t)NN * 64;     // N*64
    float* dis = B + (size_t)NN * 64;     // N
    float* t3  = dis + NN;                // N
    float* u3  = t3 + NN;                 // N

    const int nb_nodes = (NN + 255) / 256;       // 391
    const int nb_edges = (NE + 255) / 256;       // 6250
    const int nb_rows4 = NN / 4;                 // 25000 (N divisible by 4)
    const int nb_feat  = (NN * 64) / 256;        // 25000

    // Normalization
    k_init_deg<<<nb_nodes, 256, 0, stream>>>(dis);
    k_count_deg<<<nb_edges, 256, 0, stream>>>(dst, dis);
    k_finalize_dis<<<nb_nodes, 256, 0, stream>>>(dis);

    // Layer 1: ts=A, u=B
    k_gemm1<<<nb_rows4, 256, 0, stream>>>(x, W1, dis, A, B);
    k_edge_agg64<<<(NE + 3) / 4, 256, 0, stream>>>(src, dst, A, B);
    k_relu_bias<<<nb_feat, 256, 0, stream>>>(B, dis, b1, A);   // h1 = A

    // Layer 2: ts=B, u=A (aliases h1; safe — per-block rows read before write)
    k_gemm2<<<nb_rows4, 256, 0, stream>>>(A, W2, dis, B, A);
    k_edge_agg64<<<(NE + 3) / 4, 256, 0, stream>>>(src, dst, B, A);
    k_relu_bias<<<nb_feat, 256, 0, stream>>>(A, dis, b2, B);   // h2 = B

    // Layer 3
    k_gemm3<<<nb_nodes, 256, 0, stream>>>(B, W3, dis, t3, u3);
    k_edge_agg1<<<nb_edges, 256, 0, stream>>>(src, dst, t3, u3);
    k_sigmoid<<<nb_nodes, 256, 0, stream>>>(u3, dis, b3, out);
}

// Round 2
// 591.508 us; speedup vs baseline: 1.9309x; 1.9309x over previous
//
#include <hip/hip_runtime.h>
#include <math.h>

// N=100000 nodes, E=1600000 edges, features 128 -> 64 -> 64 -> 1.
#define NN 100000
#define NE 1600000

// ---------------------------------------------------------------------------
// CSR build: deg histogram -> block sums -> scan -> rowptr/cursor -> scatter.
// ---------------------------------------------------------------------------
__global__ void k_zero_deg(int* __restrict__ deg) {
    int i = blockIdx.x * 256 + threadIdx.x;
    if (i < NN) deg[i] = 0;
}

__global__ void k_hist(const int* __restrict__ dst, int* __restrict__ deg) {
    int e = blockIdx.x * 256 + threadIdx.x;
    if (e < NE) atomicAdd(&deg[dst[e]], 1);
}

__global__ void k_bsum(const int* __restrict__ deg, int* __restrict__ bsums) {
    __shared__ int s[256];
    int t = threadIdx.x;
    int i = blockIdx.x * 256 + t;
    s[t] = (i < NN) ? deg[i] : 0;
    __syncthreads();
    for (int off = 128; off > 0; off >>= 1) {
        if (t < off) s[t] += s[t + off];
        __syncthreads();
    }
    if (t == 0) bsums[blockIdx.x] = s[0];
}

// single block of 512 threads scans the 391 block sums (exclusive)
__global__ void k_scan512(const int* __restrict__ bsums, int* __restrict__ bscan) {
    __shared__ int s[512];
    int t = threadIdx.x;
    int v = (t < 391) ? bsums[t] : 0;
    s[t] = v;
    __syncthreads();
    for (int off = 1; off < 512; off <<= 1) {
        int x = (t >= off) ? s[t - off] : 0;
        __syncthreads();
        s[t] += x;
        __syncthreads();
    }
    bscan[t] = s[t] - v;  // exclusive
}

__global__ void k_rowptr(const int* __restrict__ deg, const int* __restrict__ bscan,
                         int* __restrict__ rowptr, int* __restrict__ cursor,
                         float* __restrict__ dis) {
    __shared__ int s[256];
    int t = threadIdx.x;
    int i = blockIdx.x * 256 + t;
    int d = (i < NN) ? deg[i] : 0;
    s[t] = d;
    __syncthreads();
    for (int off = 1; off < 256; off <<= 1) {
        int x = (t >= off) ? s[t - off] : 0;
        __syncthreads();
        s[t] += x;
        __syncthreads();
    }
    if (i < NN) {
        int rp = bscan[blockIdx.x] + s[t] - d;  // exclusive global prefix
        rowptr[i] = rp;
        cursor[i] = rp;
        dis[i] = rsqrtf((float)(d + 1));  // +1 self-loop; deg>=1 always
    }
    if (i == 0) rowptr[NN] = NE;
}

__global__ void k_build_csr(const int* __restrict__ src, const int* __restrict__ dst,
                            int* __restrict__ cursor, int* __restrict__ csr) {
    int e = blockIdx.x * 256 + threadIdx.x;
    if (e < NE) {
        int pos = atomicAdd(&cursor[dst[e]], 1);
        csr[pos] = src[e];
    }
}

// ---------------------------------------------------------------------------
// GEMM layer 1: ts[row][c] = (sum_k x[row][k]*W[k][c]) * dis[row]
// 64 rows x 64 cols per block; thread = 4 rows x 4 cols register tile.
// ---------------------------------------------------------------------------
#define FMA4(acc, xv)                                              \
    acc.x += xv.x * w0.x + xv.y * w1.x + xv.z * w2.x + xv.w * w3.x; \
    acc.y += xv.x * w0.y + xv.y * w1.y + xv.z * w2.y + xv.w * w3.y; \
    acc.z += xv.x * w0.z + xv.y * w1.z + xv.z * w2.z + xv.w * w3.z; \
    acc.w += xv.x * w0.w + xv.y * w1.w + xv.z * w2.w + xv.w * w3.w;

__global__ __launch_bounds__(256) void k_gemm1(
    const float* __restrict__ x, const float* __restrict__ W,
    const float* __restrict__ dis, float* __restrict__ ts) {
    __shared__ float Ws[128 * 64];   // k-major, stride 64
    __shared__ float xs[64 * 132];   // row-major, padded stride 132 (bank shift)
    int t = threadIdx.x;
    int row0 = blockIdx.x * 64;
    for (int i = t; i < 128 * 64; i += 256) Ws[i] = W[i];
    for (int i = t; i < 64 * 128; i += 256) {
        int r = i >> 7, k = i & 127;
        int gr = row0 + r;
        xs[r * 132 + k] = (gr < NN) ? x[gr * 128 + k] : 0.f;
    }
    __syncthreads();
    int cg = t & 15, rg = t >> 4;
    int col = cg * 4;
    float4 acc0 = {0, 0, 0, 0}, acc1 = {0, 0, 0, 0}, acc2 = {0, 0, 0, 0}, acc3 = {0, 0, 0, 0};
    for (int k = 0; k < 128; k += 4) {
        float4 w0 = *(const float4*)&Ws[(k + 0) * 64 + col];
        float4 w1 = *(const float4*)&Ws[(k + 1) * 64 + col];
        float4 w2 = *(const float4*)&Ws[(k + 2) * 64 + col];
        float4 w3 = *(const float4*)&Ws[(k + 3) * 64 + col];
        float4 x0 = *(const float4*)&xs[(rg * 4 + 0) * 132 + k];
        float4 x1 = *(const float4*)&xs[(rg * 4 + 1) * 132 + k];
        float4 x2 = *(const float4*)&xs[(rg * 4 + 2) * 132 + k];
        float4 x3 = *(const float4*)&xs[(rg * 4 + 3) * 132 + k];
        FMA4(acc0, x0) FMA4(acc1, x1) FMA4(acc2, x2) FMA4(acc3, x3)
    }
    float4 accs[4] = {acc0, acc1, acc2, acc3};
#pragma unroll
    for (int r = 0; r < 4; ++r) {
        int row = row0 + rg * 4 + r;
        if (row < NN) {
            float dv = dis[row];
            float4 a = accs[r];
            a.x *= dv; a.y *= dv; a.z *= dv; a.w *= dv;
            *(float4*)&ts[row * 64 + col] = a;
        }
    }
}

// GEMM layer 2: same, K=64
__global__ __launch_bounds__(256) void k_gemm2(
    const float* __restrict__ h, const float* __restrict__ W,
    const float* __restrict__ dis, float* __restrict__ ts) {
    __shared__ float Ws[64 * 64];
    __shared__ float hs[64 * 68];
    int t = threadIdx.x;
    int row0 = blockIdx.x * 64;
    for (int i = t; i < 64 * 64; i += 256) Ws[i] = W[i];
    for (int i = t; i < 64 * 64; i += 256) {
        int r = i >> 6, k = i & 63;
        int gr = row0 + r;
        hs[r * 68 + k] = (gr < NN) ? h[gr * 64 + k] : 0.f;
    }
    __syncthreads();
    int cg = t & 15, rg = t >> 4;
    int col = cg * 4;
    float4 acc0 = {0, 0, 0, 0}, acc1 = {0, 0, 0, 0}, acc2 = {0, 0, 0, 0}, acc3 = {0, 0, 0, 0};
    for (int k = 0; k < 64; k += 4) {
        float4 w0 = *(const float4*)&Ws[(k + 0) * 64 + col];
        float4 w1 = *(const float4*)&Ws[(k + 1) * 64 + col];
        float4 w2 = *(const float4*)&Ws[(k + 2) * 64 + col];
        float4 w3 = *(const float4*)&Ws[(k + 3) * 64 + col];
        float4 x0 = *(const float4*)&hs[(rg * 4 + 0) * 68 + k];
        float4 x1 = *(const float4*)&hs[(rg * 4 + 1) * 68 + k];
        float4 x2 = *(const float4*)&hs[(rg * 4 + 2) * 68 + k];
        float4 x3 = *(const float4*)&hs[(rg * 4 + 3) * 68 + k];
        FMA4(acc0, x0) FMA4(acc1, x1) FMA4(acc2, x2) FMA4(acc3, x3)
    }
    float4 accs[4] = {acc0, acc1, acc2, acc3};
#pragma unroll
    for (int r = 0; r < 4; ++r) {
        int row = row0 + rg * 4 + r;
        if (row < NN) {
            float dv = dis[row];
            float4 a = accs[r];
            a.x *= dv; a.y *= dv; a.z *= dv; a.w *= dv;
            *(float4*)&ts[row * 64 + col] = a;
        }
    }
}

// ---------------------------------------------------------------------------
// Fused aggregation + dis scale + bias + ReLU. One 64-lane wave per node,
// lane = feature. Pure gathers, no atomics. 2-way unrolled for MLP.
// ---------------------------------------------------------------------------
__global__ __launch_bounds__(256) void k_agg_relu(
    const float* __restrict__ ts, const int* __restrict__ rowptr,
    const int* __restrict__ csr, const float* __restrict__ dis,
    const float* __restrict__ b, float* __restrict__ h) {
    int node = blockIdx.x * 4 + (threadIdx.x >> 6);
    if (node >= NN) return;
    int lane = threadIdx.x & 63;
    float acc = ts[node * 64 + lane];  // self-loop term
    float acc1 = 0.f;
    int e = rowptr[node], end = rowptr[node + 1];
    for (; e + 2 <= end; e += 2) {
        int s0 = csr[e];
        int s1 = csr[e + 1];
        acc += ts[s0 * 64 + lane];
        acc1 += ts[s1 * 64 + lane];
    }
    if (e < end) acc += ts[csr[e] * 64 + lane];
    float v = (acc + acc1) * dis[node] + b[lane];
    h[node * 64 + lane] = fmaxf(v, 0.f);
}

// ---------------------------------------------------------------------------
// Layer 3 projection: t3[row] = dot(h[row], W3) * dis[row]
// ---------------------------------------------------------------------------
__global__ void k_gemm3(const float* __restrict__ h, const float* __restrict__ W3,
                        const float* __restrict__ dis, float* __restrict__ t3) {
    __shared__ float Ws[64];
    if (threadIdx.x < 64) Ws[threadIdx.x] = W3[threadIdx.x];
    __syncthreads();
    int row = blockIdx.x * 256 + threadIdx.x;
    if (row >= NN) return;
    const float4* hp = (const float4*)(h + row * 64);
    float acc = 0.f;
#pragma unroll
    for (int k = 0; k < 16; ++k) {
        float4 hv = hp[k];
        acc += hv.x * Ws[4 * k] + hv.y * Ws[4 * k + 1] + hv.z * Ws[4 * k + 2] + hv.w * Ws[4 * k + 3];
    }
    t3[row] = acc * dis[row];
}

// Fused layer-3 aggregation + sigmoid. One thread per node, scalar gathers.
__global__ void k_out(const float* __restrict__ t3, const int* __restrict__ rowptr,
                      const int* __restrict__ csr, const float* __restrict__ dis,
                      const float* __restrict__ b3, float* __restrict__ out) {
    int i = blockIdx.x * 256 + threadIdx.x;
    if (i >= NN) return;
    float acc = t3[i];
    float acc1 = 0.f;
    int e = rowptr[i], end = rowptr[i + 1];
    for (; e + 2 <= end; e += 2) {
        acc += t3[csr[e]];
        acc1 += t3[csr[e + 1]];
    }
    if (e < end) acc += t3[csr[e]];
    float z = (acc + acc1) * dis[i] + b3[0];
    out[i] = 1.f / (1.f + __expf(-z));
}

// ---------------------------------------------------------------------------
extern "C" void kernel_launch(void* const* d_in, const int* in_sizes, int n_in,
                              void* d_out, int out_size, void* d_ws, size_t ws_size,
                              hipStream_t stream) {
    const float* x  = (const float*)d_in[0];   // N x 128
    const float* W1 = (const float*)d_in[1];   // 128 x 64
    const float* b1 = (const float*)d_in[2];   // 64
    const float* W2 = (const float*)d_in[3];   // 64 x 64
    const float* b2 = (const float*)d_in[4];   // 64
    const float* W3 = (const float*)d_in[5];   // 64 x 1
    const float* b3 = (const float*)d_in[6];   // 1
    const int*   ei = (const int*)d_in[7];     // 2 x E
    const int* src = ei;
    const int* dst = ei + NE;
    float* out = (float*)d_out;

    // Workspace layout
    float* A      = (float*)d_ws;              // N*64
    float* B      = A + (size_t)NN * 64;       // N*64
    float* dis    = B + (size_t)NN * 64;       // N
    float* t3     = dis + NN;                  // N
    int*   deg    = (int*)(t3 + NN);           // N
    int*   rowptr = deg + NN;                  // N+1 (+pad)
    int*   cursor = rowptr + NN + 8;           // N
    int*   bsums  = cursor + NN;               // 512
    int*   bscan  = bsums + 512;               // 512
    int*   csr    = bscan + 512;               // E

    const int nbN = (NN + 255) / 256;   // 391
    const int nbE = (NE + 255) / 256;   // 6250
    const int nbG = (NN + 63) / 64;     // 1563 (gemm blocks, 64 rows each)
    const int nbA = (NN + 3) / 4;       // 25000 (agg blocks, 4 nodes each)

    // CSR build + normalization
    k_zero_deg<<<nbN, 256, 0, stream>>>(deg);
    k_hist<<<nbE, 256, 0, stream>>>(dst, deg);
    k_bsum<<<nbN, 256, 0, stream>>>(deg, bsums);
    k_scan512<<<1, 512, 0, stream>>>(bsums, bscan);
    k_rowptr<<<nbN, 256, 0, stream>>>(deg, bscan, rowptr, cursor, dis);
    k_build_csr<<<nbE, 256, 0, stream>>>(src, dst, cursor, csr);

    // Layer 1: ts1 = A, h1 = B
    k_gemm1<<<nbG, 256, 0, stream>>>(x, W1, dis, A);
    k_agg_relu<<<nbA, 256, 0, stream>>>(A, rowptr, csr, dis, b1, B);

    // Layer 2: ts2 = A, h2 = B
    k_gemm2<<<nbG, 256, 0, stream>>>(B, W2, dis, A);
    k_agg_relu<<<nbA, 256, 0, stream>>>(A, rowptr, csr, dis, b2, B);

    // Layer 3
    k_gemm3<<<nbN, 256, 0, stream>>>(B, W3, dis, t3);
    k_out<<<nbN, 256, 0, stream>>>(t3, rowptr, csr, dis, b3, out);
}

// Round 5
// 545.821 us; speedup vs baseline: 2.0925x; 1.0837x over previous
//
#include <hip/hip_runtime.h>
#include <math.h>

// N=100000 nodes, E=1600000 edges, features 128 -> 64 -> 64 -> 1.
#define NN 100000
#define NE 1600000
#define NSHARD 8
#define SHARD_W (NN / NSHARD)   // 12500 exactly

// ---------------------------------------------------------------------------
// CSR build: deg histogram -> block sums -> scan -> rowptr/cursor -> scatter.
// ---------------------------------------------------------------------------
__global__ void k_zero_deg(int* __restrict__ deg) {
    int i = blockIdx.x * 256 + threadIdx.x;
    if (i < NN) deg[i] = 0;
}

__global__ void k_hist(const int* __restrict__ dst, int* __restrict__ deg) {
    int e = blockIdx.x * 256 + threadIdx.x;
    if (e < NE) atomicAdd(&deg[dst[e]], 1);
}

__global__ void k_bsum(const int* __restrict__ deg, int* __restrict__ bsums) {
    __shared__ int s[256];
    int t = threadIdx.x;
    int i = blockIdx.x * 256 + t;
    s[t] = (i < NN) ? deg[i] : 0;
    __syncthreads();
    for (int off = 128; off > 0; off >>= 1) {
        if (t < off) s[t] += s[t + off];
        __syncthreads();
    }
    if (t == 0) bsums[blockIdx.x] = s[0];
}

// single block of 512 threads scans the 391 block sums (exclusive)
__global__ void k_scan512(const int* __restrict__ bsums, int* __restrict__ bscan) {
    __shared__ int s[512];
    int t = threadIdx.x;
    int v = (t < 391) ? bsums[t] : 0;
    s[t] = v;
    __syncthreads();
    for (int off = 1; off < 512; off <<= 1) {
        int x = (t >= off) ? s[t - off] : 0;
        __syncthreads();
        s[t] += x;
        __syncthreads();
    }
    bscan[t] = s[t] - v;  // exclusive
}

__global__ void k_rowptr(const int* __restrict__ deg, const int* __restrict__ bscan,
                         int* __restrict__ rowptr, int* __restrict__ cursor,
                         float* __restrict__ dis) {
    __shared__ int s[256];
    int t = threadIdx.x;
    int i = blockIdx.x * 256 + t;
    int d = (i < NN) ? deg[i] : 0;
    s[t] = d;
    __syncthreads();
    for (int off = 1; off < 256; off <<= 1) {
        int x = (t >= off) ? s[t - off] : 0;
        __syncthreads();
        s[t] += x;
        __syncthreads();
    }
    if (i < NN) {
        int rp = bscan[blockIdx.x] + s[t] - d;  // exclusive global prefix
        rowptr[i] = rp;
        cursor[i] = rp;
        dis[i] = rsqrtf((float)(d + 1));  // +1 self-loop; deg>=1 always
    }
    if (i == 0) rowptr[NN] = NE;
}

// XCD-sharded scatter: block b handles only dst in shard (b&7); blocks are
// dispatched round-robin across the 8 XCDs, so each shard's ~800KB csr slice
// stays resident+merging in ONE XCD's L2 instead of partial-dirty lines in 8.
__global__ __launch_bounds__(256) void k_build_csr(
    const int* __restrict__ src, const int* __restrict__ dst,
    int* __restrict__ cursor, int* __restrict__ csr) {
    int shard = blockIdx.x & 7;
    int bsh = blockIdx.x >> 3;
    int stride = (gridDim.x >> 3) * 256;
    int lo = shard * SHARD_W;
    int hi = lo + SHARD_W;
    for (int e = bsh * 256 + threadIdx.x; e < NE; e += stride) {
        int d = dst[e];
        if (d >= lo && d < hi) {
            int pos = atomicAdd(&cursor[d], 1);
            csr[pos] = src[e];
        }
    }
}

// ---------------------------------------------------------------------------
// GEMM layer 1: ts[row][c] = (sum_k x[row][k]*W[k][c]) * dis[row]
// 64 rows x 64 cols per block; thread = 4 rows x 4 cols register tile.
// ---------------------------------------------------------------------------
#define FMA4(acc, xv)                                              \
    acc.x += xv.x * w0.x + xv.y * w1.x + xv.z * w2.x + xv.w * w3.x; \
    acc.y += xv.x * w0.y + xv.y * w1.y + xv.z * w2.y + xv.w * w3.y; \
    acc.z += xv.x * w0.z + xv.y * w1.z + xv.z * w2.z + xv.w * w3.z; \
    acc.w += xv.x * w0.w + xv.y * w1.w + xv.z * w2.w + xv.w * w3.w;

__global__ __launch_bounds__(256) void k_gemm1(
    const float* __restrict__ x, const float* __restrict__ W,
    const float* __restrict__ dis, float* __restrict__ ts) {
    __shared__ float Ws[128 * 64];   // k-major, stride 64
    __shared__ float xs[64 * 132];   // row-major, padded stride 132 (bank shift)
    int t = threadIdx.x;
    int row0 = blockIdx.x * 64;
    for (int i = t; i < 128 * 64; i += 256) Ws[i] = W[i];
    for (int i = t; i < 64 * 128; i += 256) {
        int r = i >> 7, k = i & 127;
        int gr = row0 + r;
        xs[r * 132 + k] = (gr < NN) ? x[gr * 128 + k] : 0.f;
    }
    __syncthreads();
    int cg = t & 15, rg = t >> 4;
    int col = cg * 4;
    float4 acc0 = {0, 0, 0, 0}, acc1 = {0, 0, 0, 0}, acc2 = {0, 0, 0, 0}, acc3 = {0, 0, 0, 0};
    for (int k = 0; k < 128; k += 4) {
        float4 w0 = *(const float4*)&Ws[(k + 0) * 64 + col];
        float4 w1 = *(const float4*)&Ws[(k + 1) * 64 + col];
        float4 w2 = *(const float4*)&Ws[(k + 2) * 64 + col];
        float4 w3 = *(const float4*)&Ws[(k + 3) * 64 + col];
        float4 x0 = *(const float4*)&xs[(rg * 4 + 0) * 132 + k];
        float4 x1 = *(const float4*)&xs[(rg * 4 + 1) * 132 + k];
        float4 x2 = *(const float4*)&xs[(rg * 4 + 2) * 132 + k];
        float4 x3 = *(const float4*)&xs[(rg * 4 + 3) * 132 + k];
        FMA4(acc0, x0) FMA4(acc1, x1) FMA4(acc2, x2) FMA4(acc3, x3)
    }
    float4 accs[4] = {acc0, acc1, acc2, acc3};
#pragma unroll
    for (int r = 0; r < 4; ++r) {
        int row = row0 + rg * 4 + r;
        if (row < NN) {
            float dv = dis[row];
            float4 a = accs[r];
            a.x *= dv; a.y *= dv; a.z *= dv; a.w *= dv;
            *(float4*)&ts[row * 64 + col] = a;
        }
    }
}

// GEMM layer 2: same, K=64
__global__ __launch_bounds__(256) void k_gemm2(
    const float* __restrict__ h, const float* __restrict__ W,
    const float* __restrict__ dis, float* __restrict__ ts) {
    __shared__ float Ws[64 * 64];
    __shared__ float hs[64 * 68];
    int t = threadIdx.x;
    int row0 = blockIdx.x * 64;
    for (int i = t; i < 64 * 64; i += 256) Ws[i] = W[i];
    for (int i = t; i < 64 * 64; i += 256) {
        int r = i >> 6, k = i & 63;
        int gr = row0 + r;
        hs[r * 68 + k] = (gr < NN) ? h[gr * 64 + k] : 0.f;
    }
    __syncthreads();
    int cg = t & 15, rg = t >> 4;
    int col = cg * 4;
    float4 acc0 = {0, 0, 0, 0}, acc1 = {0, 0, 0, 0}, acc2 = {0, 0, 0, 0}, acc3 = {0, 0, 0, 0};
    for (int k = 0; k < 64; k += 4) {
        float4 w0 = *(const float4*)&Ws[(k + 0) * 64 + col];
        float4 w1 = *(const float4*)&Ws[(k + 1) * 64 + col];
        float4 w2 = *(const float4*)&Ws[(k + 2) * 64 + col];
        float4 w3 = *(const float4*)&Ws[(k + 3) * 64 + col];
        float4 x0 = *(const float4*)&hs[(rg * 4 + 0) * 68 + k];
        float4 x1 = *(const float4*)&hs[(rg * 4 + 1) * 68 + k];
        float4 x2 = *(const float4*)&hs[(rg * 4 + 2) * 68 + k];
        float4 x3 = *(const float4*)&hs[(rg * 4 + 3) * 68 + k];
        FMA4(acc0, x0) FMA4(acc1, x1) FMA4(acc2, x2) FMA4(acc3, x3)
    }
    float4 accs[4] = {acc0, acc1, acc2, acc3};
#pragma unroll
    for (int r = 0; r < 4; ++r) {
        int row = row0 + rg * 4 + r;
        if (row < NN) {
            float dv = dis[row];
            float4 a = accs[r];
            a.x *= dv; a.y *= dv; a.z *= dv; a.w *= dv;
            *(float4*)&ts[row * 64 + col] = a;
        }
    }
}

// ---------------------------------------------------------------------------
// Fused aggregation + dis scale + bias + ReLU. One 64-lane wave per node,
// lane = feature. Pure gathers, no atomics.
// ---------------------------------------------------------------------------
__global__ __launch_bounds__(256) void k_agg_relu(
    const float* __restrict__ ts, const int* __restrict__ rowptr,
    const int* __restrict__ csr, const float* __restrict__ dis,
    const float* __restrict__ b, float* __restrict__ h) {
    int node = blockIdx.x * 4 + (threadIdx.x >> 6);
    if (node >= NN) return;
    int lane = threadIdx.x & 63;
    float acc = ts[node * 64 + lane];  // self-loop term
    float acc1 = 0.f;
    int e = rowptr[node], end = rowptr[node + 1];
    for (; e + 2 <= end; e += 2) {
        int s0 = csr[e];
        int s1 = csr[e + 1];
        acc += ts[s0 * 64 + lane];
        acc1 += ts[s1 * 64 + lane];
    }
    if (e < end) acc += ts[csr[e] * 64 + lane];
    float v = (acc + acc1) * dis[node] + b[lane];
    h[node * 64 + lane] = fmaxf(v, 0.f);
}

// ---------------------------------------------------------------------------
// Layer 3 projection: t3[row] = dot(h[row], W3) * dis[row]
// ---------------------------------------------------------------------------
__global__ void k_gemm3(const float* __restrict__ h, const float* __restrict__ W3,
                        const float* __restrict__ dis, float* __restrict__ t3) {
    __shared__ float Ws[64];
    if (threadIdx.x < 64) Ws[threadIdx.x] = W3[threadIdx.x];
    __syncthreads();
    int row = blockIdx.x * 256 + threadIdx.x;
    if (row >= NN) return;
    const float4* hp = (const float4*)(h + row * 64);
    float acc = 0.f;
#pragma unroll
    for (int k = 0; k < 16; ++k) {
        float4 hv = hp[k];
        acc += hv.x * Ws[4 * k] + hv.y * Ws[4 * k + 1] + hv.z * Ws[4 * k + 2] + hv.w * Ws[4 * k + 3];
    }
    t3[row] = acc * dis[row];
}

// Fused layer-3 aggregation + sigmoid. One thread per node, scalar gathers.
__global__ void k_out(const float* __restrict__ t3, const int* __restrict__ rowptr,
                      const int* __restrict__ csr, const float* __restrict__ dis,
                      const float* __restrict__ b3, float* __restrict__ out) {
    int i = blockIdx.x * 256 + threadIdx.x;
    if (i >= NN) return;
    float acc = t3[i];
    float acc1 = 0.f;
    int e = rowptr[i], end = rowptr[i + 1];
    for (; e + 2 <= end; e += 2) {
        acc += t3[csr[e]];
        acc1 += t3[csr[e + 1]];
    }
    if (e < end) acc += t3[csr[e]];
    float z = (acc + acc1) * dis[i] + b3[0];
    out[i] = 1.f / (1.f + __expf(-z));
}

// ---------------------------------------------------------------------------
extern "C" void kernel_launch(void* const* d_in, const int* in_sizes, int n_in,
                              void* d_out, int out_size, void* d_ws, size_t ws_size,
                              hipStream_t stream) {
    const float* x  = (const float*)d_in[0];   // N x 128
    const float* W1 = (const float*)d_in[1];   // 128 x 64
    const float* b1 = (const float*)d_in[2];   // 64
    const float* W2 = (const float*)d_in[3];   // 64 x 64
    const float* b2 = (const float*)d_in[4];   // 64
    const float* W3 = (const float*)d_in[5];   // 64 x 1
    const float* b3 = (const float*)d_in[6];   // 1
    const int*   ei = (const int*)d_in[7];     // 2 x E
    const int* src = ei;
    const int* dst = ei + NE;
    float* out = (float*)d_out;

    // Workspace layout
    float* A      = (float*)d_ws;              // N*64
    float* B      = A + (size_t)NN * 64;       // N*64
    float* dis    = B + (size_t)NN * 64;       // N
    float* t3     = dis + NN;                  // N
    int*   deg    = (int*)(t3 + NN);           // N
    int*   rowptr = deg + NN;                  // N+1 (+pad)
    int*   cursor = rowptr + NN + 8;           // N
    int*   bsums  = cursor + NN;               // 512
    int*   bscan  = bsums + 512;               // 512
    int*   csr    = bscan + 512;               // E

    const int nbN = (NN + 255) / 256;   // 391
    const int nbE = (NE + 255) / 256;   // 6250
    const int nbG = (NN + 63) / 64;     // 1563
    const int nbA = (NN + 3) / 4;       // 25000

    // CSR build + normalization
    k_zero_deg<<<nbN, 256, 0, stream>>>(deg);
    k_hist<<<nbE, 256, 0, stream>>>(dst, deg);
    k_bsum<<<nbN, 256, 0, stream>>>(deg, bsums);
    k_scan512<<<1, 512, 0, stream>>>(bsums, bscan);
    k_rowptr<<<nbN, 256, 0, stream>>>(deg, bscan, rowptr, cursor, dis);
    // 2048 blocks = 256 per shard; shard = blockIdx & 7 (XCD round-robin)
    k_build_csr<<<2048, 256, 0, stream>>>(src, dst, cursor, csr);

    // Layer 1: ts1 = A, h1 = B
    k_gemm1<<<nbG, 256, 0, stream>>>(x, W1, dis, A);
    k_agg_relu<<<nbA, 256, 0, stream>>>(A, rowptr, csr, dis, b1, B);

    // Layer 2: ts2 = A, h2 = B
    k_gemm2<<<nbG, 256, 0, stream>>>(B, W2, dis, A);
    k_agg_relu<<<nbA, 256, 0, stream>>>(A, rowptr, csr, dis, b2, B);

    // Layer 3
    k_gemm3<<<nbN, 256, 0, stream>>>(B, W3, dis, t3);
    k_out<<<nbN, 256, 0, stream>>>(t3, rowptr, csr, dis, b3, out);
}

// Round 6
// 518.678 us; speedup vs baseline: 2.2020x; 1.0523x over previous
//
#include <hip/hip_runtime.h>
#include <math.h>

// N=100000 nodes, E=1600000 edges, features 128 -> 64 -> 64 -> 1.
#define NN 100000
#define NE 1600000
#define NSHARD 8
#define SHARD_W (NN / NSHARD)   // 12500 exactly

// bf16 helpers (manual, round-to-nearest-even; intermediates only)
__device__ inline unsigned f2bf(float f) {
    unsigned u = __float_as_uint(f);
    u += 0x7FFFu + ((u >> 16) & 1u);
    return u >> 16;
}
__device__ inline float bflo(unsigned v) { return __uint_as_float(v << 16); }
__device__ inline float bfhi(unsigned v) { return __uint_as_float(v & 0xFFFF0000u); }

// ---------------------------------------------------------------------------
// CSR build: deg histogram -> block sums -> scan -> rowptr/cursor -> scatter.
// ---------------------------------------------------------------------------
__global__ void k_zero_deg(int* __restrict__ deg) {
    int i = blockIdx.x * 256 + threadIdx.x;
    if (i < NN) deg[i] = 0;
}

__global__ void k_hist(const int* __restrict__ dst, int* __restrict__ deg) {
    int e = blockIdx.x * 256 + threadIdx.x;
    if (e < NE) atomicAdd(&deg[dst[e]], 1);
}

__global__ void k_bsum(const int* __restrict__ deg, int* __restrict__ bsums) {
    __shared__ int s[256];
    int t = threadIdx.x;
    int i = blockIdx.x * 256 + t;
    s[t] = (i < NN) ? deg[i] : 0;
    __syncthreads();
    for (int off = 128; off > 0; off >>= 1) {
        if (t < off) s[t] += s[t + off];
        __syncthreads();
    }
    if (t == 0) bsums[blockIdx.x] = s[0];
}

// single block of 512 threads scans the 391 block sums (exclusive)
__global__ void k_scan512(const int* __restrict__ bsums, int* __restrict__ bscan) {
    __shared__ int s[512];
    int t = threadIdx.x;
    int v = (t < 391) ? bsums[t] : 0;
    s[t] = v;
    __syncthreads();
    for (int off = 1; off < 512; off <<= 1) {
        int x = (t >= off) ? s[t - off] : 0;
        __syncthreads();
        s[t] += x;
        __syncthreads();
    }
    bscan[t] = s[t] - v;  // exclusive
}

__global__ void k_rowptr(const int* __restrict__ deg, const int* __restrict__ bscan,
                         int* __restrict__ rowptr, int* __restrict__ cursor,
                         float* __restrict__ dis) {
    __shared__ int s[256];
    int t = threadIdx.x;
    int i = blockIdx.x * 256 + t;
    int d = (i < NN) ? deg[i] : 0;
    s[t] = d;
    __syncthreads();
    for (int off = 1; off < 256; off <<= 1) {
        int x = (t >= off) ? s[t - off] : 0;
        __syncthreads();
        s[t] += x;
        __syncthreads();
    }
    if (i < NN) {
        int rp = bscan[blockIdx.x] + s[t] - d;  // exclusive global prefix
        rowptr[i] = rp;
        cursor[i] = rp;
        dis[i] = rsqrtf((float)(d + 1));  // +1 self-loop; deg>=1 always
    }
    if (i == 0) rowptr[NN] = NE;
}

// XCD-sharded scatter (each shard's csr slice merges in one XCD's L2).
__global__ __launch_bounds__(256) void k_build_csr(
    const int* __restrict__ src, const int* __restrict__ dst,
    int* __restrict__ cursor, int* __restrict__ csr) {
    int shard = blockIdx.x & 7;
    int bsh = blockIdx.x >> 3;
    int stride = (gridDim.x >> 3) * 256;
    int lo = shard * SHARD_W;
    int hi = lo + SHARD_W;
    for (int e = bsh * 256 + threadIdx.x; e < NE; e += stride) {
        int d = dst[e];
        if (d >= lo && d < hi) {
            int pos = atomicAdd(&cursor[d], 1);
            csr[pos] = src[e];
        }
    }
}

// ---------------------------------------------------------------------------
// GEMM layer 1: tsb[row][c] = bf16( (sum_k x[row][k]*W[k][c]) * dis[row] )
// 64 rows x 64 cols per block; thread = 4 rows x 4 cols register tile.
// ---------------------------------------------------------------------------
#define FMA4(acc, xv)                                              \
    acc.x += xv.x * w0.x + xv.y * w1.x + xv.z * w2.x + xv.w * w3.x; \
    acc.y += xv.x * w0.y + xv.y * w1.y + xv.z * w2.y + xv.w * w3.y; \
    acc.z += xv.x * w0.z + xv.y * w1.z + xv.z * w2.z + xv.w * w3.z; \
    acc.w += xv.x * w0.w + xv.y * w1.w + xv.z * w2.w + xv.w * w3.w;

__global__ __launch_bounds__(256) void k_gemm1(
    const float* __restrict__ x, const float* __restrict__ W,
    const float* __restrict__ dis, unsigned short* __restrict__ tsb) {
    __shared__ float Ws[128 * 64];   // k-major, stride 64
    __shared__ float xs[64 * 132];   // row-major, padded stride 132
    int t = threadIdx.x;
    int row0 = blockIdx.x * 64;
    for (int i = t; i < 128 * 64; i += 256) Ws[i] = W[i];
    for (int i = t; i < 64 * 128; i += 256) {
        int r = i >> 7, k = i & 127;
        int gr = row0 + r;
        xs[r * 132 + k] = (gr < NN) ? x[gr * 128 + k] : 0.f;
    }
    __syncthreads();
    int cg = t & 15, rg = t >> 4;
    int col = cg * 4;
    float4 acc0 = {0, 0, 0, 0}, acc1 = {0, 0, 0, 0}, acc2 = {0, 0, 0, 0}, acc3 = {0, 0, 0, 0};
    for (int k = 0; k < 128; k += 4) {
        float4 w0 = *(const float4*)&Ws[(k + 0) * 64 + col];
        float4 w1 = *(const float4*)&Ws[(k + 1) * 64 + col];
        float4 w2 = *(const float4*)&Ws[(k + 2) * 64 + col];
        float4 w3 = *(const float4*)&Ws[(k + 3) * 64 + col];
        float4 x0 = *(const float4*)&xs[(rg * 4 + 0) * 132 + k];
        float4 x1 = *(const float4*)&xs[(rg * 4 + 1) * 132 + k];
        float4 x2 = *(const float4*)&xs[(rg * 4 + 2) * 132 + k];
        float4 x3 = *(const float4*)&xs[(rg * 4 + 3) * 132 + k];
        FMA4(acc0, x0) FMA4(acc1, x1) FMA4(acc2, x2) FMA4(acc3, x3)
    }
    float4 accs[4] = {acc0, acc1, acc2, acc3};
#pragma unroll
    for (int r = 0; r < 4; ++r) {
        int row = row0 + rg * 4 + r;
        if (row < NN) {
            float dv = dis[row];
            float4 a = accs[r];
            uint2 p;
            p.x = f2bf(a.x * dv) | (f2bf(a.y * dv) << 16);
            p.y = f2bf(a.z * dv) | (f2bf(a.w * dv) << 16);
            *(uint2*)&tsb[row * 64 + col] = p;
        }
    }
}

// GEMM layer 2: reads bf16 h, writes bf16 ts. K=64.
__global__ __launch_bounds__(256) void k_gemm2(
    const unsigned short* __restrict__ hb, const float* __restrict__ W,
    const float* __restrict__ dis, unsigned short* __restrict__ tsb) {
    __shared__ float Ws[64 * 64];
    __shared__ float hs[64 * 68];
    int t = threadIdx.x;
    int row0 = blockIdx.x * 64;
    for (int i = t; i < 64 * 64; i += 256) Ws[i] = W[i];
    const unsigned* hb32 = (const unsigned*)hb;  // 2 bf16 per word, row stride 32
    for (int i = t; i < 64 * 32; i += 256) {
        int r = i >> 5, c2 = i & 31;
        int gr = row0 + r;
        unsigned v = (gr < NN) ? hb32[gr * 32 + c2] : 0u;
        hs[r * 68 + 2 * c2] = bflo(v);
        hs[r * 68 + 2 * c2 + 1] = bfhi(v);
    }
    __syncthreads();
    int cg = t & 15, rg = t >> 4;
    int col = cg * 4;
    float4 acc0 = {0, 0, 0, 0}, acc1 = {0, 0, 0, 0}, acc2 = {0, 0, 0, 0}, acc3 = {0, 0, 0, 0};
    for (int k = 0; k < 64; k += 4) {
        float4 w0 = *(const float4*)&Ws[(k + 0) * 64 + col];
        float4 w1 = *(const float4*)&Ws[(k + 1) * 64 + col];
        float4 w2 = *(const float4*)&Ws[(k + 2) * 64 + col];
        float4 w3 = *(const float4*)&Ws[(k + 3) * 64 + col];
        float4 x0 = *(const float4*)&hs[(rg * 4 + 0) * 68 + k];
        float4 x1 = *(const float4*)&hs[(rg * 4 + 1) * 68 + k];
        float4 x2 = *(const float4*)&hs[(rg * 4 + 2) * 68 + k];
        float4 x3 = *(const float4*)&hs[(rg * 4 + 3) * 68 + k];
        FMA4(acc0, x0) FMA4(acc1, x1) FMA4(acc2, x2) FMA4(acc3, x3)
    }
    float4 accs[4] = {acc0, acc1, acc2, acc3};
#pragma unroll
    for (int r = 0; r < 4; ++r) {
        int row = row0 + rg * 4 + r;
        if (row < NN) {
            float dv = dis[row];
            float4 a = accs[r];
            uint2 p;
            p.x = f2bf(a.x * dv) | (f2bf(a.y * dv) << 16);
            p.y = f2bf(a.z * dv) | (f2bf(a.w * dv) << 16);
            *(uint2*)&tsb[row * 64 + col] = p;
        }
    }
}

// ---------------------------------------------------------------------------
// Fused aggregation + dis scale + bias + ReLU, bf16 rows (128 B each).
// One 64-lane wave per node; lanes split in halves, each half gathers one
// edge per load (lane = feature PAIR), so one wave instruction covers 2
// edges. f32 accumulation; halves combined with shfl_xor(32).
// ---------------------------------------------------------------------------
__global__ __launch_bounds__(256) void k_agg_relu(
    const unsigned short* __restrict__ tsb, const int* __restrict__ rowptr,
    const int* __restrict__ csr, const float* __restrict__ dis,
    const float* __restrict__ b, unsigned short* __restrict__ hb) {
    int node = blockIdx.x * 4 + (threadIdx.x >> 6);
    if (node >= NN) return;
    int lane = threadIdx.x & 63;
    int half = lane >> 5;
    int fl = lane & 31;  // feature pair: features 2*fl, 2*fl+1
    const unsigned* ts32 = (const unsigned*)tsb;  // row stride 32 words
    float ax = 0.f, ay = 0.f;
    if (half == 0) {  // self-loop term, added once
        unsigned v = ts32[node * 32 + fl];
        ax += bflo(v); ay += bfhi(v);
    }
    int e = rowptr[node] + half, end = rowptr[node + 1];
    // per-half stride 2; unroll 2 for MLP (4 edges in flight per wave)
    for (; e + 2 < end; e += 4) {
        int s0 = csr[e];
        int s1 = csr[e + 2];
        unsigned v0 = ts32[s0 * 32 + fl];
        unsigned v1 = ts32[s1 * 32 + fl];
        ax += bflo(v0) + bflo(v1);
        ay += bfhi(v0) + bfhi(v1);
    }
    if (e < end) {
        unsigned v = ts32[csr[e] * 32 + fl];
        ax += bflo(v); ay += bfhi(v);
    }
    ax += __shfl_xor(ax, 32);
    ay += __shfl_xor(ay, 32);
    if (half == 0) {
        float dv = dis[node];
        float vx = fmaxf(ax * dv + b[2 * fl], 0.f);
        float vy = fmaxf(ay * dv + b[2 * fl + 1], 0.f);
        ((unsigned*)hb)[node * 32 + fl] = f2bf(vx) | (f2bf(vy) << 16);
    }
}

// ---------------------------------------------------------------------------
// Layer 3 projection: t3[row] = dot(h_bf16[row], W3) * dis[row]   (f32 out)
// ---------------------------------------------------------------------------
__global__ void k_gemm3(const unsigned short* __restrict__ hb, const float* __restrict__ W3,
                        const float* __restrict__ dis, float* __restrict__ t3) {
    __shared__ float Ws[64];
    if (threadIdx.x < 64) Ws[threadIdx.x] = W3[threadIdx.x];
    __syncthreads();
    int row = blockIdx.x * 256 + threadIdx.x;
    if (row >= NN) return;
    const uint4* hp = (const uint4*)(hb + row * 64);  // 8 x uint4 = 128 B
    float acc = 0.f;
#pragma unroll
    for (int k = 0; k < 8; ++k) {
        uint4 v = hp[k];
        acc += bflo(v.x) * Ws[8 * k + 0] + bfhi(v.x) * Ws[8 * k + 1]
             + bflo(v.y) * Ws[8 * k + 2] + bfhi(v.y) * Ws[8 * k + 3]
             + bflo(v.z) * Ws[8 * k + 4] + bfhi(v.z) * Ws[8 * k + 5]
             + bflo(v.w) * Ws[8 * k + 6] + bfhi(v.w) * Ws[8 * k + 7];
    }
    t3[row] = acc * dis[row];
}

// Fused layer-3 aggregation + sigmoid. One thread per node, scalar gathers.
__global__ void k_out(const float* __restrict__ t3, const int* __restrict__ rowptr,
                      const int* __restrict__ csr, const float* __restrict__ dis,
                      const float* __restrict__ b3, float* __restrict__ out) {
    int i = blockIdx.x * 256 + threadIdx.x;
    if (i >= NN) return;
    float acc = t3[i];
    float acc1 = 0.f;
    int e = rowptr[i], end = rowptr[i + 1];
    for (; e + 2 <= end; e += 2) {
        acc += t3[csr[e]];
        acc1 += t3[csr[e + 1]];
    }
    if (e < end) acc += t3[csr[e]];
    float z = (acc + acc1) * dis[i] + b3[0];
    out[i] = 1.f / (1.f + __expf(-z));
}

// ---------------------------------------------------------------------------
extern "C" void kernel_launch(void* const* d_in, const int* in_sizes, int n_in,
                              void* d_out, int out_size, void* d_ws, size_t ws_size,
                              hipStream_t stream) {
    const float* x  = (const float*)d_in[0];   // N x 128
    const float* W1 = (const float*)d_in[1];   // 128 x 64
    const float* b1 = (const float*)d_in[2];   // 64
    const float* W2 = (const float*)d_in[3];   // 64 x 64
    const float* b2 = (const float*)d_in[4];   // 64
    const float* W3 = (const float*)d_in[5];   // 64 x 1
    const float* b3 = (const float*)d_in[6];   // 1
    const int*   ei = (const int*)d_in[7];     // 2 x E
    const int* src = ei;
    const int* dst = ei + NE;
    float* out = (float*)d_out;

    // Workspace layout
    unsigned short* TSB = (unsigned short*)d_ws;          // N*64 bf16 (ts)
    unsigned short* HB  = TSB + (size_t)NN * 64;          // N*64 bf16 (h)
    float* dis    = (float*)(HB + (size_t)NN * 64);       // N
    float* t3     = dis + NN;                             // N
    int*   deg    = (int*)(t3 + NN);                      // N
    int*   rowptr = deg + NN;                             // N+1 (+pad)
    int*   cursor = rowptr + NN + 8;                      // N
    int*   bsums  = cursor + NN;                          // 512
    int*   bscan  = bsums + 512;                          // 512
    int*   csr    = bscan + 512;                          // E

    const int nbN = (NN + 255) / 256;   // 391
    const int nbE = (NE + 255) / 256;   // 6250
    const int nbG = (NN + 63) / 64;     // 1563
    const int nbA = (NN + 3) / 4;       // 25000

    // CSR build + normalization
    k_zero_deg<<<nbN, 256, 0, stream>>>(deg);
    k_hist<<<nbE, 256, 0, stream>>>(dst, deg);
    k_bsum<<<nbN, 256, 0, stream>>>(deg, bsums);
    k_scan512<<<1, 512, 0, stream>>>(bsums, bscan);
    k_rowptr<<<nbN, 256, 0, stream>>>(deg, bscan, rowptr, cursor, dis);
    k_build_csr<<<2048, 256, 0, stream>>>(src, dst, cursor, csr);

    // Layer 1
    k_gemm1<<<nbG, 256, 0, stream>>>(x, W1, dis, TSB);
    k_agg_relu<<<nbA, 256, 0, stream>>>(TSB, rowptr, csr, dis, b1, HB);

    // Layer 2
    k_gemm2<<<nbG, 256, 0, stream>>>(HB, W2, dis, TSB);
    k_agg_relu<<<nbA, 256, 0, stream>>>(TSB, rowptr, csr, dis, b2, HB);

    // Layer 3
    k_gemm3<<<nbN, 256, 0, stream>>>(HB, W3, dis, t3);
    k_out<<<nbN, 256, 0, stream>>>(t3, rowptr, csr, dis, b3, out);
}